// Round 1
// baseline (178.918 us; speedup 1.0000x reference)
//
#include <hip/hip_runtime.h>
#include <hip/hip_bf16.h>
#include <math.h>

#define Bn 2048
#define Dn 512
#define Cn 16384

typedef __bf16 v8bf __attribute__((ext_vector_type(8)));
typedef float v4f __attribute__((ext_vector_type(4)));

__device__ __forceinline__ void async16(const void* g, void* l) {
  __builtin_amdgcn_global_load_lds(
      (const __attribute__((address_space(1))) char*)g,
      (__attribute__((address_space(3))) char*)l, 16, 0, 0);
}

// ---------------- prep: norms, scales, bf16 conversion ----------------
__global__ __launch_bounds__(256) void prep_kernel(
    const float* __restrict__ w, const float* __restrict__ x,
    __hip_bfloat16* __restrict__ wbf, __hip_bfloat16* __restrict__ xbf,
    float* __restrict__ fscale, float* __restrict__ ysqA, float* __restrict__ yrA,
    float* __restrict__ xsA, float* __restrict__ xrA)
{
  int row = blockIdx.x;
  int tid = threadIdx.x;
  bool isW = row < Cn;
  const float* src = isW ? (w + (size_t)row * Dn) : (x + (size_t)(row - Cn) * Dn);
  float2 v = ((const float2*)src)[tid];
  float ss = v.x * v.x + v.y * v.y;
  #pragma unroll
  for (int d = 1; d < 64; d <<= 1) ss += __shfl_xor(ss, d);
  __shared__ float red[4];
  if ((tid & 63) == 0) red[tid >> 6] = ss;
  __syncthreads();
  float total = red[0] + red[1] + red[2] + red[3];

  __hip_bfloat162 o;
  o.x = __float2bfloat16(v.x);
  o.y = __float2bfloat16(v.y);
  if (isW) {
    ((__hip_bfloat162*)(wbf + (size_t)row * Dn))[tid] = o;
    if (tid == 0) {
      float n = fmaxf(sqrtf(total), 1e-7f);
      float t = tanhf(n);          // c=1: tanh(sqrt_c * norm)
      float tc = fminf(t, 0.95f);  // radius clip folded into the scale
      fscale[row] = tc / n;        // proto = fscale * w
      float ys = tc * tc;          // ||proto||^2
      ysqA[row] = ys;
      yrA[row] = 1.f / (1.f - fminf(ys, 1.f - 1e-5f));
    }
  } else {
    int r = row - Cn;
    ((__hip_bfloat162*)(xbf + (size_t)r * Dn))[tid] = o;
    if (tid == 0) {
      xsA[r] = total;  // raw x_sq (used unclamped in diff_sq)
      xrA[r] = 1.f / (1.f - fminf(total, 1.f - 1e-5f));
    }
  }
}

// ---------------- fused bf16 MFMA GEMM + hyperbolic-arcface epilogue ----------------
// m97 structure: 128x128 tile, BK=32, 4 waves (2x2), 16x16x32 bf16 MFMA,
// global_load_lds width=16 staging. Epilogue computes exp(logit) row-sums.
__global__ __launch_bounds__(256) void gemm_loss_kernel(
    const __hip_bfloat16* __restrict__ xbf, const __hip_bfloat16* __restrict__ wbf,
    const float* __restrict__ fscale, const float* __restrict__ ysqA,
    const float* __restrict__ yrA, const float* __restrict__ xsA,
    const float* __restrict__ xrA, const int* __restrict__ labels,
    float* __restrict__ rowsum, float* __restrict__ lablog)
{
  __shared__ __bf16 As[128 * 32];
  __shared__ __bf16 Ws[128 * 32];

  const int bid = blockIdx.x;
  const int mt = bid & 15;   // 16 m-tiles
  const int nt = bid >> 4;   // 128 n-tiles
  const int mBase = mt * 128;
  const int nBase = nt * 128;
  const int tid = threadIdx.x;
  const int lane = tid & 63;
  const int wave = tid >> 6;
  const int quad = lane >> 4;
  const int l16 = lane & 15;
  const int waveM = wave >> 1;
  const int waveN = wave & 1;

  v4f acc[4][4];
  #pragma unroll
  for (int i = 0; i < 4; ++i)
    #pragma unroll
    for (int j = 0; j < 4; ++j)
      acc[i][j] = (v4f){0.f, 0.f, 0.f, 0.f};

  const char* Abase = (const char*)(xbf + (size_t)mBase * Dn);
  const char* Wbase = (const char*)(wbf + (size_t)nBase * Dn);
  char* AsB = (char*)As;
  char* WsB = (char*)Ws;
  // 512 16B-chunks per tile (128 rows x 64B), 256 threads -> 2 passes each
  const int ch0 = tid, ch1 = tid + 256;
  const int ar0 = ch0 >> 2, ao0 = (ch0 & 3) * 16;
  const int ar1 = ch1 >> 2, ao1 = (ch1 & 3) * 16;
  const int arow = waveM * 64 + l16;
  const int brow = waveN * 64 + l16;
  const int koff = quad * 8;

  for (int kt = 0; kt < Dn; kt += 32) {
    __syncthreads();  // previous tile's ds_reads done before overwrite
    const char* Ak = Abase + kt * 2;
    const char* Wk = Wbase + kt * 2;
    async16(Ak + ar0 * (Dn * 2) + ao0, AsB + ch0 * 16);
    async16(Ak + ar1 * (Dn * 2) + ao1, AsB + ch1 * 16);
    async16(Wk + ar0 * (Dn * 2) + ao0, WsB + ch0 * 16);
    async16(Wk + ar1 * (Dn * 2) + ao1, WsB + ch1 * 16);
    __syncthreads();  // drains vmcnt (global_load_lds) before barrier

    v8bf af[4], bfr[4];
    #pragma unroll
    for (int i = 0; i < 4; ++i)
      af[i] = *(const v8bf*)&As[(arow + i * 16) * 32 + koff];
    #pragma unroll
    for (int j = 0; j < 4; ++j)
      bfr[j] = *(const v8bf*)&Ws[(brow + j * 16) * 32 + koff];
    #pragma unroll
    for (int i = 0; i < 4; ++i)
      #pragma unroll
      for (int j = 0; j < 4; ++j)
        acc[i][j] = __builtin_amdgcn_mfma_f32_16x16x32_bf16(af[i], bfr[j], acc[i][j], 0, 0, 0);
  }

  // ---- epilogue: logits -> exp -> per-row partial sums ----
  int colv[4];
  float fj[4], ysqj[4], yrj[4];
  #pragma unroll
  for (int j = 0; j < 4; ++j) {
    int col = nBase + waveN * 64 + j * 16 + l16;
    colv[j] = col;
    fj[j] = fscale[col];
    ysqj[j] = ysqA[col];
    yrj[j] = yrA[col];
  }
  #pragma unroll
  for (int i = 0; i < 4; ++i) {
    int rbase = mBase + waveM * 64 + i * 16 + quad * 4;
    #pragma unroll
    for (int r = 0; r < 4; ++r) {
      int row = rbase + r;
      float xs = xsA[row];
      float xr = xrA[row];
      int lab = labels[row];
      float partial = 0.f;
      #pragma unroll
      for (int j = 0; j < 4; ++j) {
        float xy = fj[j] * acc[i][j][r];                  // x . proto
        float diff = fmaxf(xs + ysqj[j] - 2.f * xy, 0.f); // ||x-y||^2
        // denom clamp max(denom,1e-7) provably dead: ry>=0.0975 (0.95 clip), rx>=1e-5
        float z = fmaf(2.f * diff, xr * yrj[j], 1.f);     // arg of arccosh
        z = fmaxf(z, 1.f + 1e-7f);
        float sq = sqrtf(fmaf(z, z, -1.f));
        // sims = exp(-arccosh(z)) = 1/(z + sqrt(z^2-1)) -- no cancellation
        float sims = __builtin_amdgcn_rcpf(z + sq);
        float cosv = fminf(fmaxf(fmaf(2.f, sims, -1.f), -1.f), 1.f);
        float logit;
        if (colv[j] == lab) {
          float sine = sqrtf(fmaxf(fmaf(-cosv, cosv, 1.f), 1e-7f));
          float ph = (cosv > -0.8775825619f)
                         ? (cosv * 0.8775825619f - sine * 0.4794255386f)
                         : (cosv - 0.2397127693f);
          logit = 64.f * ph;
          lablog[row] = logit;  // unique writer lane
        } else {
          logit = 64.f * cosv;
        }
        partial += __expf(logit);  // fixed-shift logsumexp: exp(-64) is normal fp32
      }
      // reduce over the 16 lanes holding this row's cols
      partial += __shfl_xor(partial, 1);
      partial += __shfl_xor(partial, 2);
      partial += __shfl_xor(partial, 4);
      partial += __shfl_xor(partial, 8);
      if (l16 == 0) atomicAdd(&rowsum[row], partial);
    }
  }
}

// ---------------- final: loss = mean(log(sum) - label_logit) ----------------
__global__ __launch_bounds__(256) void loss_kernel(
    const float* __restrict__ rowsum, const float* __restrict__ lablog,
    float* __restrict__ out)
{
  int tid = threadIdx.x;
  float acc = 0.f;
  for (int r = tid; r < Bn; r += 256)
    acc += logf(rowsum[r]) - lablog[r];
  #pragma unroll
  for (int d = 1; d < 64; d <<= 1) acc += __shfl_xor(acc, d);
  __shared__ float red[4];
  if ((tid & 63) == 0) red[tid >> 6] = acc;
  __syncthreads();
  if (tid == 0) out[0] = (red[0] + red[1] + red[2] + red[3]) / (float)Bn;
}

extern "C" void kernel_launch(void* const* d_in, const int* in_sizes, int n_in,
                              void* d_out, int out_size, void* d_ws, size_t ws_size,
                              hipStream_t stream) {
  (void)in_sizes; (void)n_in; (void)out_size; (void)ws_size;
  const float* emb = (const float*)d_in[0];
  const int* labels = (const int*)d_in[1];
  const float* weight = (const float*)d_in[2];
  float* out = (float*)d_out;

  char* p = (char*)d_ws;
  __hip_bfloat16* wbf = (__hip_bfloat16*)p; p += (size_t)Cn * Dn * 2;  // 16 MB
  __hip_bfloat16* xbf = (__hip_bfloat16*)p; p += (size_t)Bn * Dn * 2;  // 2 MB
  float* fscale = (float*)p; p += (size_t)Cn * 4;
  float* ysqA  = (float*)p; p += (size_t)Cn * 4;
  float* yrA   = (float*)p; p += (size_t)Cn * 4;
  float* xsA   = (float*)p; p += (size_t)Bn * 4;
  float* xrA   = (float*)p; p += (size_t)Bn * 4;
  float* rowsum = (float*)p; p += (size_t)Bn * 4;
  float* lablog = (float*)p; p += (size_t)Bn * 4;

  hipMemsetAsync(rowsum, 0, Bn * sizeof(float), stream);
  prep_kernel<<<Cn + Bn, 256, 0, stream>>>(weight, emb, wbf, xbf, fscale, ysqA, yrA, xsA, xrA);
  gemm_loss_kernel<<<(Bn / 128) * (Cn / 128), 256, 0, stream>>>(
      xbf, wbf, fscale, ysqA, yrA, xsA, xrA, labels, rowsum, lablog);
  loss_kernel<<<1, 256, 0, stream>>>(rowsum, lablog, out);
}

// Round 2
// 156.347 us; speedup vs baseline: 1.1444x; 1.1444x over previous
//
#include <hip/hip_runtime.h>
#include <hip/hip_bf16.h>
#include <math.h>

#define Bn 2048
#define Dn 512
#define Cn 16384

typedef __bf16 v8bf __attribute__((ext_vector_type(8)));
typedef float v4f __attribute__((ext_vector_type(4)));

__device__ __forceinline__ void async16(const void* g, void* l) {
  __builtin_amdgcn_global_load_lds(
      (const __attribute__((address_space(1))) char*)g,
      (__attribute__((address_space(3))) char*)l, 16, 0, 0);
}

// ---------------- prep: wave-per-row norms, scales, bf16 conversion ----------------
__global__ __launch_bounds__(256) void prep_kernel(
    const float* __restrict__ w, const float* __restrict__ x,
    __hip_bfloat16* __restrict__ wbf, __hip_bfloat16* __restrict__ xbf,
    float* __restrict__ fscale, float* __restrict__ ysqA, float* __restrict__ yrA,
    float* __restrict__ xsA, float* __restrict__ xrA)
{
  int gw = (blockIdx.x * 256 + threadIdx.x) >> 6;  // wave id == row, rows 0..Cn+Bn-1
  int lane = threadIdx.x & 63;
  bool isW = gw < Cn;
  const float* src = isW ? (w + (size_t)gw * Dn) : (x + (size_t)(gw - Cn) * Dn);
  const float4* s4 = (const float4*)src;
  float4 a = s4[lane * 2], b = s4[lane * 2 + 1];  // 32 B/lane, coalesced
  float ss = a.x * a.x + a.y * a.y + a.z * a.z + a.w * a.w
           + b.x * b.x + b.y * b.y + b.z * b.z + b.w * b.w;
  #pragma unroll
  for (int d = 1; d < 64; d <<= 1) ss += __shfl_xor(ss, d);

  union { __hip_bfloat16 h[8]; int4 i4; } u;
  u.h[0] = __float2bfloat16(a.x); u.h[1] = __float2bfloat16(a.y);
  u.h[2] = __float2bfloat16(a.z); u.h[3] = __float2bfloat16(a.w);
  u.h[4] = __float2bfloat16(b.x); u.h[5] = __float2bfloat16(b.y);
  u.h[6] = __float2bfloat16(b.z); u.h[7] = __float2bfloat16(b.w);
  __hip_bfloat16* dst = isW ? (wbf + (size_t)gw * Dn) : (xbf + (size_t)(gw - Cn) * Dn);
  ((int4*)dst)[lane] = u.i4;  // 16 B/lane, coalesced

  if (lane == 0) {
    if (isW) {
      float n = fmaxf(sqrtf(ss), 1e-7f);
      float t = tanhf(n);           // c=1: tanh(sqrt_c * norm)
      float tc = fminf(t, 0.95f);   // radius clip folded into scale
      fscale[gw] = tc / n;          // proto = fscale * w
      float ys = tc * tc;           // ||proto||^2
      ysqA[gw] = ys;
      yrA[gw] = 1.f / (1.f - fminf(ys, 1.f - 1e-5f));
    } else {
      int r = gw - Cn;
      xsA[r] = ss;
      xrA[r] = 1.f / (1.f - fminf(ss, 1.f - 1e-5f));
    }
  }
}

// ---------------- fused bf16 MFMA GEMM + slim epilogue ----------------
// 128x128 tile, BK=32, 4 waves, 16x16x32 bf16 MFMA, global_load_lds width=16.
// LDS layout swizzled: 16B chunk (r,c) stored at slot col (c + r + (r>>2))&3
// -> ds_read_b128 bank-group (4r + slot)%8 hits all 8 groups exactly 2x per
// 16 lanes = conflict-free (2-way is free per m136).
__global__ __launch_bounds__(256) void gemm_kernel(
    const __hip_bfloat16* __restrict__ xbf, const __hip_bfloat16* __restrict__ wbf,
    const float* __restrict__ fscale, const float* __restrict__ ysqA,
    const float* __restrict__ yrA, const float* __restrict__ xsA,
    const float* __restrict__ xrA, float* __restrict__ partials)
{
  __shared__ __bf16 As[128 * 32];
  __shared__ __bf16 Ws[128 * 32];

  const int bid = blockIdx.x;
  const int mt = bid & 15;   // 16 m-tiles (consecutive blocks share nt -> W-tile L2 reuse)
  const int nt = bid >> 4;   // 128 n-tiles
  const int mBase = mt * 128;
  const int nBase = nt * 128;
  const int tid = threadIdx.x;
  const int lane = tid & 63;
  const int wave = tid >> 6;
  const int quad = lane >> 4;
  const int l16 = lane & 15;
  const int waveM = wave >> 1;
  const int waveN = wave & 1;

  v4f acc[4][4];
  #pragma unroll
  for (int i = 0; i < 4; ++i)
    #pragma unroll
    for (int j = 0; j < 4; ++j)
      acc[i][j] = (v4f){0.f, 0.f, 0.f, 0.f};

  // staging: 512 slots/tile; slot s -> row s>>2, slot-col s&3,
  // global chunk col c = (slotcol - r - (r>>2)) & 3  (inverse swizzle)
  const int s0 = tid, s1 = tid + 256;
  const int r0 = s0 >> 2, c0 = ((s0 & 3) - r0 - (r0 >> 2)) & 3;
  const int r1 = s1 >> 2, c1 = ((s1 & 3) - r1 - (r1 >> 2)) & 3;
  const char* Ag0 = (const char*)(xbf + (size_t)(mBase + r0) * Dn) + c0 * 16;
  const char* Ag1 = (const char*)(xbf + (size_t)(mBase + r1) * Dn) + c1 * 16;
  const char* Wg0 = (const char*)(wbf + (size_t)(nBase + r0) * Dn) + c0 * 16;
  const char* Wg1 = (const char*)(wbf + (size_t)(nBase + r1) * Dn) + c1 * 16;
  char* AsB = (char*)As;
  char* WsB = (char*)Ws;

  // hoisted swizzled LDS read addresses (constant across kt)
  int aoff[4], boff[4];
  #pragma unroll
  for (int i = 0; i < 4; ++i) {
    int ra = waveM * 64 + l16 + i * 16;
    aoff[i] = (ra * 4 + ((quad + ra + (ra >> 2)) & 3)) * 16;
    int rb = waveN * 64 + l16 + i * 16;
    boff[i] = (rb * 4 + ((quad + rb + (rb >> 2)) & 3)) * 16;
  }

  #pragma unroll
  for (int kt = 0; kt < 16; ++kt) {
    __syncthreads();  // previous tile's ds_reads done before overwrite
    async16(Ag0 + kt * 64, AsB + s0 * 16);
    async16(Ag1 + kt * 64, AsB + s1 * 16);
    async16(Wg0 + kt * 64, WsB + s0 * 16);
    async16(Wg1 + kt * 64, WsB + s1 * 16);
    __syncthreads();  // drains vmcnt before use

    v8bf af[4], bfr[4];
    #pragma unroll
    for (int i = 0; i < 4; ++i) af[i] = *(const v8bf*)(AsB + aoff[i]);
    #pragma unroll
    for (int j = 0; j < 4; ++j) bfr[j] = *(const v8bf*)(WsB + boff[j]);
    #pragma unroll
    for (int i = 0; i < 4; ++i)
      #pragma unroll
      for (int j = 0; j < 4; ++j)
        acc[i][j] = __builtin_amdgcn_mfma_f32_16x16x32_bf16(af[i], bfr[j], acc[i][j], 0, 0, 0);
  }

  // ---- slim epilogue: no label branch, no dead clamps ----
  // z >= 1 by construction => sims = 1/(z+sqrt(z^2-1)) in (0,1] => cos in (-1,1]
  // logit = 64*(2*sims-1) = fma(128, sims, -64)
  float fj[4], ysqj[4], yrj[4], gj[4];
  #pragma unroll
  for (int j = 0; j < 4; ++j) {
    int col = nBase + waveN * 64 + j * 16 + l16;
    float f = fscale[col];
    fj[j] = f;
    gj[j] = -2.f * f;
    ysqj[j] = ysqA[col];
    yrj[j] = yrA[col];
  }
  #pragma unroll
  for (int i = 0; i < 4; ++i) {
    #pragma unroll
    for (int r = 0; r < 4; ++r) {
      int row = mBase + waveM * 64 + i * 16 + quad * 4 + r;
      float xs = xsA[row];
      float xr2 = 2.f * xrA[row];
      float partial = 0.f;
      #pragma unroll
      for (int j = 0; j < 4; ++j) {
        float diff = fmaxf(fmaf(gj[j], acc[i][j][r], xs + ysqj[j]), 0.f);
        float z = fmaf(diff, xr2 * yrj[j], 1.f);
        float sq = sqrtf(fmaf(z, z, -1.f));
        float sims = __builtin_amdgcn_rcpf(z + sq);  // exp(-arccosh(z)), no cancellation
        partial += __expf(fmaf(128.f, sims, -64.f)); // fixed-shift logsumexp
      }
      partial += __shfl_xor(partial, 1);
      partial += __shfl_xor(partial, 2);
      partial += __shfl_xor(partial, 4);
      partial += __shfl_xor(partial, 8);
      if (l16 == 0) partials[(size_t)row * 256 + nt * 2 + waveN] = partial;
    }
  }
}

// ---------------- final: label fix + row reduce + mean ----------------
__global__ __launch_bounds__(256) void final_kernel(
    const float* __restrict__ x, const float* __restrict__ w,
    const int* __restrict__ labels, const float* __restrict__ fscale,
    const float* __restrict__ ysqA, const float* __restrict__ yrA,
    const float* __restrict__ xsA, const float* __restrict__ xrA,
    const float* __restrict__ partials, float* __restrict__ out)
{
  int row = blockIdx.x * 4 + (threadIdx.x >> 6);  // wave per row
  int lane = threadIdx.x & 63;
  const float* pr = partials + (size_t)row * 256;
  float sum = pr[lane] + pr[lane + 64] + pr[lane + 128] + pr[lane + 192];

  int lab = labels[row];
  const float4* xv = (const float4*)(x + (size_t)row * Dn);
  const float4* wv = (const float4*)(w + (size_t)lab * Dn);
  float4 a0 = xv[lane * 2], a1 = xv[lane * 2 + 1];
  float4 b0 = wv[lane * 2], b1 = wv[lane * 2 + 1];
  float dot = a0.x * b0.x + a0.y * b0.y + a0.z * b0.z + a0.w * b0.w
            + a1.x * b1.x + a1.y * b1.y + a1.z * b1.z + a1.w * b1.w;
  #pragma unroll
  for (int d = 1; d < 64; d <<= 1) {
    sum += __shfl_xor(sum, d);
    dot += __shfl_xor(dot, d);
  }

  __shared__ float red[4];
  if (lane == 0) {
    float xy = fscale[lab] * dot;  // fp32 label logit
    float diff = fmaxf(xsA[row] + ysqA[lab] - 2.f * xy, 0.f);
    float z = fmaf(2.f * diff, xrA[row] * yrA[lab], 1.f);
    float sq = sqrtf(fmaf(z, z, -1.f));
    float sims = 1.f / (z + sq);
    float cosv = fmaf(2.f, sims, -1.f);
    float sine = sqrtf(fmaxf(fmaf(-cosv, cosv, 1.f), 1e-7f));
    float phi = (cosv > -0.8775825619f)
                    ? (cosv * 0.8775825619f - sine * 0.4794255386f)
                    : (cosv - 0.2397127693f);
    float e_cos = __expf(64.f * cosv);
    float e_phi = __expf(64.f * phi);
    // replace plain-cos label term in the row-sum with the margin term
    float term = logf(sum - e_cos + e_phi) - 64.f * phi;
    red[threadIdx.x >> 6] = term;
  }
  __syncthreads();
  if (threadIdx.x == 0)
    atomicAdd(out, (red[0] + red[1] + red[2] + red[3]) * (1.f / (float)Bn));
}

extern "C" void kernel_launch(void* const* d_in, const int* in_sizes, int n_in,
                              void* d_out, int out_size, void* d_ws, size_t ws_size,
                              hipStream_t stream) {
  (void)in_sizes; (void)n_in; (void)out_size; (void)ws_size;
  const float* emb = (const float*)d_in[0];
  const int* labels = (const int*)d_in[1];
  const float* weight = (const float*)d_in[2];
  float* out = (float*)d_out;

  char* p = (char*)d_ws;
  __hip_bfloat16* wbf = (__hip_bfloat16*)p; p += (size_t)Cn * Dn * 2;  // 16 MB
  __hip_bfloat16* xbf = (__hip_bfloat16*)p; p += (size_t)Bn * Dn * 2;  // 2 MB
  float* fscale = (float*)p; p += (size_t)Cn * 4;
  float* ysqA  = (float*)p; p += (size_t)Cn * 4;
  float* yrA   = (float*)p; p += (size_t)Cn * 4;
  float* xsA   = (float*)p; p += (size_t)Bn * 4;
  float* xrA   = (float*)p; p += (size_t)Bn * 4;
  float* partials = (float*)p; p += (size_t)Bn * 256 * 4;  // 2 MB, written-once (no init)

  hipMemsetAsync(out, 0, sizeof(float), stream);  // atomicAdd target
  prep_kernel<<<(Cn + Bn) / 4, 256, 0, stream>>>(weight, emb, wbf, xbf, fscale, ysqA, yrA, xsA, xrA);
  gemm_kernel<<<(Bn / 128) * (Cn / 128), 256, 0, stream>>>(
      xbf, wbf, fscale, ysqA, yrA, xsA, xrA, partials);
  final_kernel<<<Bn / 4, 256, 0, stream>>>(emb, weight, labels, fscale, ysqA, yrA, xsA, xrA, partials, out);
}

// Round 3
// 150.945 us; speedup vs baseline: 1.1853x; 1.0358x over previous
//
#include <hip/hip_runtime.h>
#include <hip/hip_bf16.h>
#include <math.h>

#define Bn 2048
#define Dn 512
#define Cn 16384

typedef __bf16 v8bf __attribute__((ext_vector_type(8)));
typedef float v4f __attribute__((ext_vector_type(4)));

__device__ __forceinline__ void async16(const void* g, void* l) {
  __builtin_amdgcn_global_load_lds(
      (const __attribute__((address_space(1))) char*)g,
      (__attribute__((address_space(3))) char*)l, 16, 0, 0);
}

// ---------------- prep: wave-per-row norms, scales, bf16 conversion ----------------
__global__ __launch_bounds__(256) void prep_kernel(
    const float* __restrict__ w, const float* __restrict__ x,
    __hip_bfloat16* __restrict__ wbf, __hip_bfloat16* __restrict__ xbf,
    float* __restrict__ fscale, float* __restrict__ ysqA, float* __restrict__ yrA,
    float* __restrict__ xsA, float* __restrict__ xrA)
{
  int gw = (blockIdx.x * 256 + threadIdx.x) >> 6;  // wave id == row
  int lane = threadIdx.x & 63;
  bool isW = gw < Cn;
  const float* src = isW ? (w + (size_t)gw * Dn) : (x + (size_t)(gw - Cn) * Dn);
  const float4* s4 = (const float4*)src;
  float4 a = s4[lane * 2], b = s4[lane * 2 + 1];  // 32 B/lane, coalesced
  float ss = a.x * a.x + a.y * a.y + a.z * a.z + a.w * a.w
           + b.x * b.x + b.y * b.y + b.z * b.z + b.w * b.w;
  #pragma unroll
  for (int d = 1; d < 64; d <<= 1) ss += __shfl_xor(ss, d);

  union { __hip_bfloat16 h[8]; int4 i4; } u;
  u.h[0] = __float2bfloat16(a.x); u.h[1] = __float2bfloat16(a.y);
  u.h[2] = __float2bfloat16(a.z); u.h[3] = __float2bfloat16(a.w);
  u.h[4] = __float2bfloat16(b.x); u.h[5] = __float2bfloat16(b.y);
  u.h[6] = __float2bfloat16(b.z); u.h[7] = __float2bfloat16(b.w);
  __hip_bfloat16* dst = isW ? (wbf + (size_t)gw * Dn) : (xbf + (size_t)(gw - Cn) * Dn);
  ((int4*)dst)[lane] = u.i4;  // 16 B/lane, coalesced

  if (lane == 0) {
    if (isW) {
      float n = fmaxf(sqrtf(ss), 1e-7f);
      float t = tanhf(n);           // c=1: tanh(sqrt_c * norm)
      float tc = fminf(t, 0.95f);   // radius clip folded into scale
      fscale[gw] = tc / n;          // proto = fscale * w
      float ys = tc * tc;           // ||proto||^2
      ysqA[gw] = ys;
      yrA[gw] = 1.f / (1.f - fminf(ys, 1.f - 1e-5f));
    } else {
      int r = gw - Cn;
      xsA[r] = ss;
      xrA[r] = 1.f / (1.f - fminf(ss, 1.f - 1e-5f));
    }
  }
}

// ---------------- fused bf16 MFMA GEMM, double-buffered, BK=64 ----------------
// 128x128 tile, BK=64 (8 iters), 2x LDS buffers (64 KB total), prefetch issued
// right after the barrier so the vmcnt(0) drain at the NEXT barrier lands after
// ~500 cyc of ds_read+MFMA compute. XCD swizzle keeps each XCD's W-band (2 MB)
// + X (2 MB) resident in its 4 MiB L2.
// LDS rows are 8 x 16B chunks; chunk (r,c) stored at slot col c ^ (r&7) so the
// quad-strided ds_read_b128 covers all 8 bank groups 2x (free 2-way).
__global__ __launch_bounds__(256) void gemm_kernel(
    const __hip_bfloat16* __restrict__ xbf, const __hip_bfloat16* __restrict__ wbf,
    const float* __restrict__ fscale, const float* __restrict__ ysqA,
    const float* __restrict__ yrA, const float* __restrict__ xsA,
    const float* __restrict__ xrA, float* __restrict__ partials)
{
  __shared__ char lds[65536];  // [As0 16K][Ws0 16K][As1 16K][Ws1 16K]

  const int bid = blockIdx.x;
  const int xcd = bid & 7;          // dispatch is round-robin across XCDs (heuristic)
  const int loc = bid >> 3;         // 0..255 within this XCD
  const int mt  = loc & 15;         // m varies fastest -> 16 blocks share one W tile
  const int nt  = (xcd << 4) | (loc >> 4);  // contiguous 16-nt band per XCD
  const int mBase = mt * 128;
  const int nBase = nt * 128;
  const int tid = threadIdx.x;
  const int lane = tid & 63;
  const int wave = tid >> 6;
  const int quad = lane >> 4;
  const int l16 = lane & 15;
  const int waveM = wave >> 1;
  const int waveN = wave & 1;

  v4f acc[4][4];
  #pragma unroll
  for (int i = 0; i < 4; ++i)
    #pragma unroll
    for (int j = 0; j < 4; ++j)
      acc[i][j] = (v4f){0.f, 0.f, 0.f, 0.f};

  // staging: 1024 slots per 16 KB buffer; slot s -> row r=s>>3, slot-col s&7,
  // global chunk col c = (s&7) ^ (r&7)  (xor swizzle, self-inverse)
  const char* gA[4]; const char* gW[4]; int lOff[4];
  #pragma unroll
  for (int p = 0; p < 4; ++p) {
    int s = tid + p * 256;
    int r = s >> 3;
    int c = (s & 7) ^ (r & 7);
    gA[p] = (const char*)xbf + (size_t)(mBase + r) * (Dn * 2) + c * 16;
    gW[p] = (const char*)wbf + (size_t)(nBase + r) * (Dn * 2) + c * 16;
    lOff[p] = s * 16;
  }
  char* AsBuf[2] = {lds, lds + 32768};
  char* WsBuf[2] = {lds + 16384, lds + 49152};

  // frag LDS read offsets for h=0 (k-half 0); h=1 is ^64 (chunk col bit 2)
  int aoffs[4], boffs[4];
  #pragma unroll
  for (int i = 0; i < 4; ++i) {
    int ra = waveM * 64 + i * 16 + l16;
    aoffs[i] = ra * 128 + ((quad ^ (ra & 7)) * 16);
    int rb = waveN * 64 + i * 16 + l16;
    boffs[i] = rb * 128 + ((quad ^ (rb & 7)) * 16);
  }

  // prologue: fill buffer 0 with kt=0
  #pragma unroll
  for (int p = 0; p < 4; ++p) {
    async16(gA[p], AsBuf[0] + lOff[p]);
    async16(gW[p], WsBuf[0] + lOff[p]);
  }

  #pragma unroll
  for (int kt = 0; kt < 8; ++kt) {
    const int cur = kt & 1, nxt = cur ^ 1;
    __syncthreads();  // drains vmcnt: buf[cur] ready; lgkm: prior reads of buf[nxt] done
    if (kt < 7) {     // prefetch next K-slab into the other buffer (drained at NEXT barrier)
      #pragma unroll
      for (int p = 0; p < 4; ++p) {
        async16(gA[p] + (kt + 1) * 128, AsBuf[nxt] + lOff[p]);
        async16(gW[p] + (kt + 1) * 128, WsBuf[nxt] + lOff[p]);
      }
    }
    const char* Ab = AsBuf[cur];
    const char* Wb = WsBuf[cur];
    #pragma unroll
    for (int h = 0; h < 2; ++h) {
      v8bf af[4], bfr[4];
      #pragma unroll
      for (int i = 0; i < 4; ++i) af[i] = *(const v8bf*)(Ab + (aoffs[i] ^ (h * 64)));
      #pragma unroll
      for (int j = 0; j < 4; ++j) bfr[j] = *(const v8bf*)(Wb + (boffs[j] ^ (h * 64)));
      #pragma unroll
      for (int i = 0; i < 4; ++i)
        #pragma unroll
        for (int j = 0; j < 4; ++j)
          acc[i][j] = __builtin_amdgcn_mfma_f32_16x16x32_bf16(af[i], bfr[j], acc[i][j], 0, 0, 0);
    }
  }

  // ---- slim epilogue: z>=1 by construction => no clamps needed ----
  float ysqj[4], yrj[4], gj[4];
  #pragma unroll
  for (int j = 0; j < 4; ++j) {
    int col = nBase + waveN * 64 + j * 16 + l16;
    gj[j] = -2.f * fscale[col];
    ysqj[j] = ysqA[col];
    yrj[j] = yrA[col];
  }
  #pragma unroll
  for (int i = 0; i < 4; ++i) {
    #pragma unroll
    for (int r = 0; r < 4; ++r) {
      int row = mBase + waveM * 64 + i * 16 + quad * 4 + r;
      float xs = xsA[row];
      float xr2 = 2.f * xrA[row];
      float partial = 0.f;
      #pragma unroll
      for (int j = 0; j < 4; ++j) {
        float diff = fmaxf(fmaf(gj[j], acc[i][j][r], xs + ysqj[j]), 0.f);
        float z = fmaf(diff, xr2 * yrj[j], 1.f);
        float sq = sqrtf(fmaf(z, z, -1.f));
        float sims = __builtin_amdgcn_rcpf(z + sq);  // exp(-arccosh(z)), no cancellation
        partial += __expf(fmaf(128.f, sims, -64.f)); // fixed-shift logsumexp
      }
      partial += __shfl_xor(partial, 1);
      partial += __shfl_xor(partial, 2);
      partial += __shfl_xor(partial, 4);
      partial += __shfl_xor(partial, 8);
      if (l16 == 0) partials[(size_t)row * 256 + nt * 2 + waveN] = partial;
    }
  }
}

// ---------------- final: per-row label fix + term (no atomics) ----------------
__global__ __launch_bounds__(256) void final_kernel(
    const float* __restrict__ x, const float* __restrict__ w,
    const int* __restrict__ labels, const float* __restrict__ fscale,
    const float* __restrict__ ysqA, const float* __restrict__ yrA,
    const float* __restrict__ xsA, const float* __restrict__ xrA,
    const float* __restrict__ partials, float* __restrict__ terms)
{
  int row = blockIdx.x * 4 + (threadIdx.x >> 6);  // wave per row
  int lane = threadIdx.x & 63;
  const float* pr = partials + (size_t)row * 256;
  float sum = pr[lane] + pr[lane + 64] + pr[lane + 128] + pr[lane + 192];

  int lab = labels[row];
  const float4* xv = (const float4*)(x + (size_t)row * Dn);
  const float4* wv = (const float4*)(w + (size_t)lab * Dn);
  float4 a0 = xv[lane * 2], a1 = xv[lane * 2 + 1];
  float4 b0 = wv[lane * 2], b1 = wv[lane * 2 + 1];
  float dot = a0.x * b0.x + a0.y * b0.y + a0.z * b0.z + a0.w * b0.w
            + a1.x * b1.x + a1.y * b1.y + a1.z * b1.z + a1.w * b1.w;
  #pragma unroll
  for (int d = 1; d < 64; d <<= 1) {
    sum += __shfl_xor(sum, d);
    dot += __shfl_xor(dot, d);
  }

  if (lane == 0) {
    float xy = fscale[lab] * dot;  // fp32 label logit
    float diff = fmaxf(xsA[row] + ysqA[lab] - 2.f * xy, 0.f);
    float z = fmaf(2.f * diff, xrA[row] * yrA[lab], 1.f);
    float sq = sqrtf(fmaf(z, z, -1.f));
    float sims = 1.f / (z + sq);
    float cosv = fmaf(2.f, sims, -1.f);
    float sine = sqrtf(fmaxf(fmaf(-cosv, cosv, 1.f), 1e-7f));
    float phi = (cosv > -0.8775825619f)
                    ? (cosv * 0.8775825619f - sine * 0.4794255386f)
                    : (cosv - 0.2397127693f);
    float e_cos = __expf(64.f * cosv);
    float e_phi = __expf(64.f * phi);
    // swap the plain-cos label term in the bf16 row-sum for the fp32 margin term
    terms[row] = logf(sum - e_cos + e_phi) - 64.f * phi;
  }
}

// ---------------- reduce: mean over rows ----------------
__global__ __launch_bounds__(256) void reduce_kernel(
    const float* __restrict__ terms, float* __restrict__ out)
{
  int tid = threadIdx.x;
  float acc = 0.f;
  for (int r = tid; r < Bn; r += 256) acc += terms[r];
  #pragma unroll
  for (int d = 1; d < 64; d <<= 1) acc += __shfl_xor(acc, d);
  __shared__ float red[4];
  if ((tid & 63) == 0) red[tid >> 6] = acc;
  __syncthreads();
  if (tid == 0) out[0] = (red[0] + red[1] + red[2] + red[3]) * (1.f / (float)Bn);
}

extern "C" void kernel_launch(void* const* d_in, const int* in_sizes, int n_in,
                              void* d_out, int out_size, void* d_ws, size_t ws_size,
                              hipStream_t stream) {
  (void)in_sizes; (void)n_in; (void)out_size; (void)ws_size;
  const float* emb = (const float*)d_in[0];
  const int* labels = (const int*)d_in[1];
  const float* weight = (const float*)d_in[2];
  float* out = (float*)d_out;

  char* p = (char*)d_ws;
  __hip_bfloat16* wbf = (__hip_bfloat16*)p; p += (size_t)Cn * Dn * 2;  // 16 MB
  __hip_bfloat16* xbf = (__hip_bfloat16*)p; p += (size_t)Bn * Dn * 2;  // 2 MB
  float* fscale = (float*)p; p += (size_t)Cn * 4;
  float* ysqA  = (float*)p; p += (size_t)Cn * 4;
  float* yrA   = (float*)p; p += (size_t)Cn * 4;
  float* xsA   = (float*)p; p += (size_t)Bn * 4;
  float* xrA   = (float*)p; p += (size_t)Bn * 4;
  float* partials = (float*)p; p += (size_t)Bn * 256 * 4;  // 2 MB, written-once
  float* terms = (float*)p; p += (size_t)Bn * 4;           // written-once

  prep_kernel<<<(Cn + Bn) / 4, 256, 0, stream>>>(weight, emb, wbf, xbf, fscale, ysqA, yrA, xsA, xrA);
  gemm_kernel<<<(Bn / 128) * (Cn / 128), 256, 0, stream>>>(
      xbf, wbf, fscale, ysqA, yrA, xsA, xrA, partials);
  final_kernel<<<Bn / 4, 256, 0, stream>>>(emb, weight, labels, fscale, ysqA, yrA, xsA, xrA, partials, terms);
  reduce_kernel<<<1, 256, 0, stream>>>(terms, out);
}